// Round 4
// baseline (217.773 us; speedup 1.0000x reference)
//
#include <hip/hip_runtime.h>
#include <stdint.h>

#define NN 8192
#define NE 16384
#define DD 64
#define GCAP 512          // cap on generator count (expected ~150, Binomial(8192, ~2%))
#define GQCAP 128         // GCAP/4 generator-quads
#define SLICES 32         // j-dimension split: 32 slices x 256 j
#define NEGV -1e10f
#define TINYF 1.17549435e-38f
#define SQRT2F 1.41421356237f

// ---------------- JAX threefry2x32 (partitionable mode) ----------------
__device__ __forceinline__ uint2 tf2x32(uint32_t k0, uint32_t k1, uint32_t x0, uint32_t x1) {
  uint32_t ks2 = k0 ^ k1 ^ 0x1BD11BDAu;
  x0 += k0; x1 += k1;
#define TF_R(r) { x0 += x1; x1 = (x1 << (r)) | (x1 >> (32 - (r))); x1 ^= x0; }
  TF_R(13) TF_R(15) TF_R(26) TF_R(6)
  x0 += k1; x1 += ks2 + 1u;
  TF_R(17) TF_R(29) TF_R(16) TF_R(24)
  x0 += ks2; x1 += k0 + 2u;
  TF_R(13) TF_R(15) TF_R(26) TF_R(6)
  x0 += k0; x1 += k1 + 3u;
  TF_R(17) TF_R(29) TF_R(16) TF_R(24)
  x0 += k1; x1 += ks2 + 4u;
  TF_R(13) TF_R(15) TF_R(26) TF_R(6)
  x0 += ks2; x1 += k0 + 5u;
#undef TF_R
  return make_uint2(x0, x1);
}
__device__ __forceinline__ uint2 jax_subkey(uint32_t i) { return tf2x32(0u, 42u, 0u, i); }
__device__ __forceinline__ uint32_t rbits(uint2 k, uint32_t idx) {
  uint2 r = tf2x32(k.x, k.y, 0u, idx);
  return r.x ^ r.y;
}
__device__ __forceinline__ float u01f(uint32_t b) {
  return __uint_as_float((b >> 9) | 0x3F800000u) - 1.0f;
}
__device__ __forceinline__ float erfinv_xla(float x) {
  float w = -log1pf(-x * x);
  float p;
  if (w < 5.0f) {
    w -= 2.5f;
    p = 2.81022636e-08f;
    p = fmaf(p, w, 3.43273939e-07f);
    p = fmaf(p, w, -3.5233877e-06f);
    p = fmaf(p, w, -4.39150654e-06f);
    p = fmaf(p, w, 0.00021858087f);
    p = fmaf(p, w, -0.00125372503f);
    p = fmaf(p, w, -0.00417768164f);
    p = fmaf(p, w, 0.246640727f);
    p = fmaf(p, w, 1.50140941f);
  } else {
    w = sqrtf(w) - 3.0f;
    p = -0.000200214257f;
    p = fmaf(p, w, 0.000100950558f);
    p = fmaf(p, w, 0.00134934322f);
    p = fmaf(p, w, -0.00367342844f);
    p = fmaf(p, w, 0.00573950773f);
    p = fmaf(p, w, -0.0076224613f);
    p = fmaf(p, w, 0.00943887047f);
    p = fmaf(p, w, 1.00167406f);
    p = fmaf(p, w, 2.83297682f);
  }
  return p * x;
}
__device__ __forceinline__ float jax_normal(uint2 k, uint32_t idx) {
  float f = u01f(rbits(k, idx));
  float lo = __uint_as_float(0xBF7FFFFFu);
  float u = fmaxf(lo, f * 2.0f + lo);
  return SQRT2F * erfinv_xla(u);
}
__device__ __forceinline__ float jax_gumbel(uint2 k, uint32_t idx) {
  float f = u01f(rbits(k, idx));
  float u = fmaxf(TINYF, f + TINYF);
  return -logf(-logf(u));
}
__device__ __forceinline__ int aload(int* p) {
  return __hip_atomic_load(p, __ATOMIC_ACQUIRE, __HIP_MEMORY_SCOPE_AGENT);
}

// ws scalars: 0=G(atomic) 1=e_active 2=allowed 3=kept_total 4=n_gens 5=gq-done

// ---- K1: gens + hn + atomic generator append; extra block: aedges cumsum ----
__global__ void sg_front(const float* __restrict__ nodes, const float* __restrict__ Wp,
                         const float* __restrict__ bp, const float* __restrict__ anodes,
                         const float* __restrict__ aedges, int* __restrict__ sc,
                         int* __restrict__ gens0, int* __restrict__ gidx,
                         int* __restrict__ c, float* __restrict__ hn) {
  if (blockIdx.x == NN / 4) {
    // inclusive int cumsum of (aedges != 0), single block
    __shared__ int ts[256];
    int t = threadIdx.x;
    int base = t * 64;
    uint64_t bits = 0;
    int s = 0;
    const float4* a4 = (const float4*)(aedges + base);
    for (int k4 = 0; k4 < 16; k4++) {
      float4 v = a4[k4];
      if (v.x != 0.0f) { bits |= 1ull << (4 * k4 + 0); s++; }
      if (v.y != 0.0f) { bits |= 1ull << (4 * k4 + 1); s++; }
      if (v.z != 0.0f) { bits |= 1ull << (4 * k4 + 2); s++; }
      if (v.w != 0.0f) { bits |= 1ull << (4 * k4 + 3); s++; }
    }
    ts[t] = s;
    __syncthreads();
    for (int off = 1; off < 256; off <<= 1) {
      int add = (t >= off) ? ts[t - off] : 0;
      __syncthreads();
      ts[t] += add;
      __syncthreads();
    }
    int run = ts[t] - s;
    for (int k = 0; k < 64; k++) {
      run += (int)((bits >> k) & 1ull);
      c[base + k] = run;
    }
    if (t == 255) { sc[1] = ts[255]; sc[2] = NE - ts[255] - 1; }
    return;
  }
  int lane = threadIdx.x & 63;
  int i = blockIdx.x * 4 + (threadIdx.x >> 6);
  float v = nodes[i * DD + lane];
  float ss = v * v;
  float dp = v * Wp[lane];
  for (int off = 32; off > 0; off >>= 1) {
    ss += __shfl_xor(ss, off, 64);
    dp += __shfl_xor(dp, off, 64);
  }
  if (lane == 0) {
    hn[i] = ss;
    float x = dp + bp[0];
    float p = 1.0f / (1.0f + expf(-x));
    uint2 kp = jax_subkey(0u);
    float u = u01f(rbits(kp, (uint32_t)i));
    int g = (u < p * anodes[i]) ? 1 : 0;
    gens0[i] = g;
    if (g) {
      int slot = atomicAdd(&sc[0], 1);   // unordered append; consumers are id-keyed
      if (slot < NN) gidx[slot] = i;
    }
  }
}

// ---- K2: partial argmax + (last-slice block) final sel/exist + (last-quad) rank ----
__global__ __launch_bounds__(256) void sg_partsel(
    const float* __restrict__ nodes, const float* __restrict__ anodes,
    const float* __restrict__ hn, const int* __restrict__ gidx,
    int* __restrict__ sc, int* __restrict__ slicedone,
    const float* __restrict__ Wq, const float* __restrict__ bq,
    const int* __restrict__ senders, const int* __restrict__ receivers,
    const int* __restrict__ gens0, float* __restrict__ party, int* __restrict__ partj,
    int* __restrict__ selby, int* __restrict__ keptby,
    int* __restrict__ fid, int* __restrict__ fsel) {
  __shared__ float sq[4][DD];
  __shared__ float sqn[4];
  __shared__ int si[4];
  __shared__ float wy[4][4];
  __shared__ int wj[4][4];
  __shared__ int winflag, rankflag;
  __shared__ int jsout[4];
  __shared__ int exu[4];
  __shared__ int ts[256];
  int G = min(sc[0], GCAP);
  int nGq = (G + 3) >> 2;
  int total = nGq * SLICES;
  int t = threadIdx.x;
  int wid = t >> 6, lane = t & 63;
  uint2 ks = jax_subkey(2u);
  int* partyi = (int*)party;

  if (total == 0) {
    if (blockIdx.x == 0 && t == 0) { sc[3] = 0; sc[4] = 0; }
    return;
  }

  for (int item = blockIdx.x; item < total; item += gridDim.x) {
    int gq = item / SLICES, s = item % SLICES;
    int g0 = gq * 4;
    __syncthreads();   // guard LDS reuse across iterations
    if (t < 4) { int g = g0 + t; si[t] = (g < G) ? gidx[g] : -1; }
    __syncthreads();
    if (t < DD) {
      // recompute 4 queries (bitwise-identical op order every time)
      int i0 = si[0] < 0 ? 0 : si[0];
      int i1 = si[1] < 0 ? 0 : si[1];
      int i2 = si[2] < 0 ? 0 : si[2];
      int i3 = si[3] < 0 ? 0 : si[3];
      float a0 = bq[t], a1 = a0, a2 = a0, a3 = a0;
      for (int k = 0; k < DD; k++) {
        float w = Wq[k * DD + t];
        a0 = fmaf(nodes[i0 * DD + k], w, a0);
        a1 = fmaf(nodes[i1 * DD + k], w, a1);
        a2 = fmaf(nodes[i2 * DD + k], w, a2);
        a3 = fmaf(nodes[i3 * DD + k], w, a3);
      }
      sq[0][t] = a0; sq[1][t] = a1; sq[2][t] = a2; sq[3][t] = a3;
      float s0 = a0 * a0, s1 = a1 * a1, s2 = a2 * a2, s3 = a3 * a3;
      for (int off = 32; off > 0; off >>= 1) {
        s0 += __shfl_xor(s0, off, 64);
        s1 += __shfl_xor(s1, off, 64);
        s2 += __shfl_xor(s2, off, 64);
        s3 += __shfl_xor(s3, off, 64);
      }
      if (t == 0) { sqn[0] = s0; sqn[1] = s1; sqn[2] = s2; sqn[3] = s3; }
    }
    __syncthreads();
    int j = s * 256 + t;
    float4 nv[16];
    const float4* np4 = (const float4*)(nodes + (size_t)j * DD);
    for (int k4 = 0; k4 < 16; k4++) nv[k4] = np4[k4];
    float hnj = hn[j];
    float act = anodes[j];
    float yy[4];
    for (int u = 0; u < 4; u++) {
      int iu = si[u];
      if (iu < 0) { yy[u] = -INFINITY; continue; }
      float num = 0.0f;
      for (int k4 = 0; k4 < 16; k4++) {
        const float4 qv = *(const float4*)&sq[u][4 * k4];
        num += nv[k4].x * qv.x + nv[k4].y * qv.y + nv[k4].z * qv.z + nv[k4].w * qv.w;
      }
      float denom = sqrtf(sqn[u] * hnj) + 1e-8f;
      float sco = num / denom;
      sco = fminf(fmaxf(sco, -10000.0f), 10000.0f);
      if (!(act > 0.0f)) sco = NEGV;
      if (j == iu) sco = NEGV;
      yy[u] = sco + jax_gumbel(ks, (uint32_t)iu * (uint32_t)NN + (uint32_t)j);
    }
    for (int u = 0; u < 4; u++) {
      float y = yy[u];
      int bj = j;
      for (int off = 32; off > 0; off >>= 1) {
        float oy = __shfl_xor(y, off, 64);
        int oj = __shfl_xor(bj, off, 64);
        if (oy > y || (oy == y && oj < bj)) { y = oy; bj = oj; }
      }
      if (lane == 0) { wy[u][wid] = y; wj[u][wid] = bj; }
    }
    __syncthreads();
    if (t < 4) {
      int u = t;
      if (g0 + u < G) {
        float y = wy[u][0];
        int bj = wj[u][0];
        for (int w = 1; w < 4; w++)
          if (wy[u][w] > y || (wy[u][w] == y && wj[u][w] < bj)) { y = wy[u][w]; bj = wj[u][w]; }
        party[(g0 + u) * SLICES + s] = y;
        partj[(g0 + u) * SLICES + s] = bj;
      }
      __threadfence();   // publish before counter bump
    }
    __syncthreads();
    if (t == 0) {
      int old = atomicAdd(&slicedone[gq], 1);
      winflag = (old == SLICES - 1) ? 1 : 0;
    }
    __syncthreads();
    if (winflag) {
      // --- final argmax over 32 slices for this quad ---
      if (t < 64) {
        for (int u = 0; u < 4; u++) {
          if (g0 + u >= G) { if (lane == 0) jsout[u] = 0; continue; }
          float y; int bj;
          if (lane < SLICES) {
            int idx = (g0 + u) * SLICES + lane;
            y = __int_as_float(aload(&partyi[idx]));
            bj = aload(&partj[idx]);
          } else { y = -INFINITY; bj = 0x7fffffff; }
          for (int off = 32; off > 0; off >>= 1) {
            float oy = __shfl_xor(y, off, 64);
            int oj = __shfl_xor(bj, off, 64);
            if (oy > y || (oy == y && oj < bj)) { y = oy; bj = oj; }
          }
          if (lane == 0) jsout[u] = bj;
        }
      }
      if (t < 4) exu[t] = 0;
      __syncthreads();
      // --- duplicate-edge scan for 4 gens at once ---
      int i0 = si[0], i1 = si[1], i2 = si[2], i3 = si[3];
      int j0 = jsout[0], j1 = jsout[1], j2 = jsout[2], j3 = jsout[3];
      int f0 = 0, f1 = 0, f2 = 0, f3 = 0;
      for (int e = t; e < NE; e += 256) {
        int se = senders[e], re = receivers[e];
        f0 |= (se == i0 && re == j0);
        f1 |= (se == i1 && re == j1);
        f2 |= (se == i2 && re == j2);
        f3 |= (se == i3 && re == j3);
      }
      if (f0) exu[0] = 1;
      if (f1) exu[1] = 1;
      if (f2) exu[2] = 1;
      if (f3) exu[3] = 1;
      __syncthreads();
      if (t < 4) {
        if (si[t] >= 0) {
          selby[si[t]] = jsout[t];
          keptby[si[t]] = exu[t] ? 0 : 1;
        }
        __threadfence();
      }
      __syncthreads();
      if (t == 0) {
        int old = atomicAdd(&sc[5], 1);
        rankflag = (old == nGq - 1) ? 1 : 0;
      }
      __syncthreads();
      if (rankflag) {
        // --- rank kept generators in node-id order (all quads now done) ---
        int base = t * (NN / 256);
        int cnt = 0;
        for (int k = 0; k < NN / 256; k++) {
          int id = base + k;
          if (gens0[id]) cnt += aload(&keptby[id]);
        }
        ts[t] = cnt;
        __syncthreads();
        for (int off = 1; off < 256; off <<= 1) {
          int add = (t >= off) ? ts[t - off] : 0;
          __syncthreads();
          ts[t] += add;
          __syncthreads();
        }
        int r = ts[t] - cnt;
        for (int k = 0; k < NN / 256; k++) {
          int id = base + k;
          if (gens0[id] && aload(&keptby[id])) {
            fid[r] = id;
            fsel[r] = aload(&selby[id]);
            r++;
          }
        }
        if (t == 255) {
          int kt = ts[255];
          int allowed = sc[2];
          int ng = kt > 0 ? kt : 0;
          if (ng > allowed) ng = allowed;
          sc[3] = kt; sc[4] = ng;
        }
      }
    }
  }
}

// ---- K3: fused output writer: new_edges + nsend/nrec/naedges ----
__global__ void sg_write(const float* __restrict__ edges, const float* __restrict__ aedges,
                         const int* __restrict__ senders, const int* __restrict__ receivers,
                         const int* __restrict__ c, const int* __restrict__ sc,
                         const int* __restrict__ fid, const int* __restrict__ fsel,
                         float* __restrict__ out_edges, float* __restrict__ out_send,
                         float* __restrict__ out_rec, float* __restrict__ out_na) {
  int t4 = blockIdx.x * 256 + threadIdx.x;  // float4 index, NE*16 total
  float4 v = ((const float4*)edges)[t4];
  int e = t4 >> 4;
  int n = sc[4];
  int ce = c[e];
  int pidx = e - n - 1;
  int prev = (pidx >= 0) ? c[pidx] : 0;
  int na = ((ce - prev) > 0 && e != NE - 1) ? 1 : 0;
  float mv = na ? (1.0f - aedges[e]) : 0.0f;
  if (mv != 0.0f) {
    uint2 ke = jax_subkey(1u);
    uint32_t b = (uint32_t)t4 * 4u;
    v.x += jax_normal(ke, b + 0u) * mv;
    v.y += jax_normal(ke, b + 1u) * mv;
    v.z += jax_normal(ke, b + 2u) * mv;
    v.w += jax_normal(ke, b + 3u) * mv;
  }
  ((float4*)out_edges)[t4] = v;
  if ((t4 & 15) == 0) {
    int ea = sc[1], kept = sc[3];
    float ns, nr;
    if (!na) {
      ns = nr = (float)(NN - 1);
    } else if (mv > 0.0f) {
      int r = e - ea;
      bool ok = (r >= 0 && r < kept);
      ns = ok ? (float)fid[r] : 0.0f;   // segment_sum default is 0
      nr = ok ? (float)fsel[r] : 0.0f;
    } else {
      ns = (float)senders[e];
      nr = (float)receivers[e];
    }
    out_send[e] = ns;
    out_rec[e] = nr;
    out_na[e] = (float)na;
  }
}

extern "C" void kernel_launch(void* const* d_in, const int* in_sizes, int n_in,
                              void* d_out, int out_size, void* d_ws, size_t ws_size,
                              hipStream_t stream) {
  const float* nodes     = (const float*)d_in[0];
  const float* edges     = (const float*)d_in[1];
  const int*   receivers = (const int*)d_in[2];
  const int*   senders   = (const int*)d_in[3];
  const float* anodes    = (const float*)d_in[4];
  const float* aedges    = (const float*)d_in[5];
  const float* Wq        = (const float*)d_in[6];
  const float* bq        = (const float*)d_in[7];
  const float* Wp        = (const float*)d_in[8];
  const float* bp        = (const float*)d_in[9];

  float* out       = (float*)d_out;
  float* out_edges = out;
  float* out_send  = out + (size_t)NE * DD;
  float* out_rec   = out_send + NE;
  float* out_na    = out_rec + NE;

  int* sc        = (int*)d_ws;              // 16 scalars
  int* slicedone = sc + 16;                 // GQCAP
  int* gens0     = slicedone + GQCAP;       // NN
  int* gidx      = gens0 + NN;              // NN (append, capped reads)
  int* selby     = gidx + NN;               // NN (id-keyed)
  int* keptby    = selby + NN;              // NN (id-keyed)
  int* fid       = keptby + NN;             // GCAP
  int* fsel      = fid + GCAP;              // GCAP
  int* c         = fsel + GCAP;             // NE
  int* partj     = c + NE;                  // GCAP*SLICES
  float* hn      = (float*)(partj + GCAP * SLICES);  // NN
  float* party   = hn + NN;                 // GCAP*SLICES

  // zero counters: sc[0..15] + slicedone[0..GQCAP) = 576 bytes
  hipMemsetAsync(d_ws, 0, (16 + GQCAP) * sizeof(int), stream);

  sg_front  <<<NN / 4 + 1, 256, 0, stream>>>(nodes, Wp, bp, anodes, aedges, sc, gens0,
                                             gidx, c, hn);
  sg_partsel<<<2048, 256, 0, stream>>>(nodes, anodes, hn, gidx, sc, slicedone, Wq, bq,
                                       senders, receivers, gens0, party, partj, selby,
                                       keptby, fid, fsel);
  sg_write  <<<NE * DD / 4 / 256, 256, 0, stream>>>(edges, aedges, senders, receivers, c, sc,
                                                    fid, fsel, out_edges, out_send, out_rec,
                                                    out_na);
}

// Round 5
// 149.410 us; speedup vs baseline: 1.4576x; 1.4576x over previous
//
#include <hip/hip_runtime.h>
#include <stdint.h>

#define NN 8192
#define NE 16384
#define DD 64
#define GCAP 512          // cap on generator count (expected ~150, Binomial(8192, ~2%))
#define SLICES 32         // j-dimension split: 32 slices x 256 j
#define NEGV -1e10f
#define TINYF 1.17549435e-38f
#define SQRT2F 1.41421356237f

// ---------------- JAX threefry2x32 (partitionable mode) ----------------
__device__ __forceinline__ uint2 tf2x32(uint32_t k0, uint32_t k1, uint32_t x0, uint32_t x1) {
  uint32_t ks2 = k0 ^ k1 ^ 0x1BD11BDAu;
  x0 += k0; x1 += k1;
#define TF_R(r) { x0 += x1; x1 = (x1 << (r)) | (x1 >> (32 - (r))); x1 ^= x0; }
  TF_R(13) TF_R(15) TF_R(26) TF_R(6)
  x0 += k1; x1 += ks2 + 1u;
  TF_R(17) TF_R(29) TF_R(16) TF_R(24)
  x0 += ks2; x1 += k0 + 2u;
  TF_R(13) TF_R(15) TF_R(26) TF_R(6)
  x0 += k0; x1 += k1 + 3u;
  TF_R(17) TF_R(29) TF_R(16) TF_R(24)
  x0 += k1; x1 += ks2 + 4u;
  TF_R(13) TF_R(15) TF_R(26) TF_R(6)
  x0 += ks2; x1 += k0 + 5u;
#undef TF_R
  return make_uint2(x0, x1);
}
__device__ __forceinline__ uint2 jax_subkey(uint32_t i) { return tf2x32(0u, 42u, 0u, i); }
__device__ __forceinline__ uint32_t rbits(uint2 k, uint32_t idx) {
  uint2 r = tf2x32(k.x, k.y, 0u, idx);
  return r.x ^ r.y;
}
__device__ __forceinline__ float u01f(uint32_t b) {
  return __uint_as_float((b >> 9) | 0x3F800000u) - 1.0f;
}
__device__ __forceinline__ float erfinv_xla(float x) {
  float w = -log1pf(-x * x);
  float p;
  if (w < 5.0f) {
    w -= 2.5f;
    p = 2.81022636e-08f;
    p = fmaf(p, w, 3.43273939e-07f);
    p = fmaf(p, w, -3.5233877e-06f);
    p = fmaf(p, w, -4.39150654e-06f);
    p = fmaf(p, w, 0.00021858087f);
    p = fmaf(p, w, -0.00125372503f);
    p = fmaf(p, w, -0.00417768164f);
    p = fmaf(p, w, 0.246640727f);
    p = fmaf(p, w, 1.50140941f);
  } else {
    w = sqrtf(w) - 3.0f;
    p = -0.000200214257f;
    p = fmaf(p, w, 0.000100950558f);
    p = fmaf(p, w, 0.00134934322f);
    p = fmaf(p, w, -0.00367342844f);
    p = fmaf(p, w, 0.00573950773f);
    p = fmaf(p, w, -0.0076224613f);
    p = fmaf(p, w, 0.00943887047f);
    p = fmaf(p, w, 1.00167406f);
    p = fmaf(p, w, 2.83297682f);
  }
  return p * x;
}
__device__ __forceinline__ float jax_normal(uint2 k, uint32_t idx) {
  float f = u01f(rbits(k, idx));
  float lo = __uint_as_float(0xBF7FFFFFu);
  float u = fmaxf(lo, f * 2.0f + lo);
  return SQRT2F * erfinv_xla(u);
}
__device__ __forceinline__ float jax_gumbel(uint2 k, uint32_t idx) {
  float f = u01f(rbits(k, idx));
  float u = fmaxf(TINYF, f + TINYF);
  return -logf(-logf(u));
}

// ws scalars: 0=G 1=e_active 2=allowed 3=kept_total 4=n_gens

// ---- K1: per-node hn, probs, bernoulli gens (one wave64 per node) ----
__global__ void sg_gens(const float* __restrict__ nodes, const float* __restrict__ Wp,
                        const float* __restrict__ bp, const float* __restrict__ anodes,
                        int* __restrict__ gens0, float* __restrict__ hn) {
  int lane = threadIdx.x & 63;
  int i = blockIdx.x * 4 + (threadIdx.x >> 6);
  float v = nodes[i * DD + lane];
  float ss = v * v;
  float dp = v * Wp[lane];
  for (int off = 32; off > 0; off >>= 1) {
    ss += __shfl_xor(ss, off, 64);
    dp += __shfl_xor(dp, off, 64);
  }
  if (lane == 0) {
    hn[i] = ss;
    float x = dp + bp[0];
    float p = 1.0f / (1.0f + expf(-x));
    uint2 kp = jax_subkey(0u);
    float u = u01f(rbits(kp, (uint32_t)i));
    gens0[i] = (u < p * anodes[i]) ? 1 : 0;
  }
}

// ---- K2: fused single-block: cumsum(active_edges) + compact(generators) ----
__global__ void sg_scan(const float* __restrict__ aedges, const int* __restrict__ gens0,
                        int* __restrict__ c, int* __restrict__ gidx, int* __restrict__ sc) {
  __shared__ int ts[256];
  int t = threadIdx.x;
  // --- part 1: inclusive int cumsum of (aedges != 0) ---
  int base = t * 64;
  uint64_t bits = 0;
  int s = 0;
  const float4* a4 = (const float4*)(aedges + base);
  for (int k4 = 0; k4 < 16; k4++) {
    float4 v = a4[k4];
    if (v.x != 0.0f) { bits |= 1ull << (4 * k4 + 0); s++; }
    if (v.y != 0.0f) { bits |= 1ull << (4 * k4 + 1); s++; }
    if (v.z != 0.0f) { bits |= 1ull << (4 * k4 + 2); s++; }
    if (v.w != 0.0f) { bits |= 1ull << (4 * k4 + 3); s++; }
  }
  ts[t] = s;
  __syncthreads();
  for (int off = 1; off < 256; off <<= 1) {
    int add = (t >= off) ? ts[t - off] : 0;
    __syncthreads();
    ts[t] += add;
    __syncthreads();
  }
  int run = ts[t] - s;
  for (int k = 0; k < 64; k++) {
    run += (int)((bits >> k) & 1ull);
    c[base + k] = run;
  }
  if (t == 255) { sc[1] = ts[255]; sc[2] = NE - ts[255] - 1; }
  __syncthreads();
  // --- part 2: compact generator node ids ---
  int b2 = t * 32;
  uint32_t gb = 0;
  int s2 = 0;
  const int4* g4 = (const int4*)(gens0 + b2);
  for (int k4 = 0; k4 < 8; k4++) {
    int4 v = g4[k4];
    if (v.x) { gb |= 1u << (4 * k4 + 0); s2++; }
    if (v.y) { gb |= 1u << (4 * k4 + 1); s2++; }
    if (v.z) { gb |= 1u << (4 * k4 + 2); s2++; }
    if (v.w) { gb |= 1u << (4 * k4 + 3); s2++; }
  }
  ts[t] = s2;
  __syncthreads();
  for (int off = 1; off < 256; off <<= 1) {
    int add = (t >= off) ? ts[t - off] : 0;
    __syncthreads();
    ts[t] += add;
    __syncthreads();
  }
  int r = ts[t] - s2;
  for (int k = 0; k < 32; k++)
    if ((gb >> k) & 1u) gidx[r++] = b2 + k;
  if (t == 255) sc[0] = ts[255];
}

// ---- K3: queries for generator rows: qg[g][:] = nodes[i] @ Wq + bq, qn[g] ----
__global__ void sg_query(const float* __restrict__ nodes, const float* __restrict__ Wq,
                         const float* __restrict__ bq, const int* __restrict__ gidx,
                         const int* __restrict__ sc, float* __restrict__ qg,
                         float* __restrict__ qnrm) {
  int g = blockIdx.x;
  int G = min(sc[0], GCAP);
  if (g >= G) return;
  int i = gidx[g];
  int t = threadIdx.x;  // 64 threads
  const float* nr = nodes + (size_t)i * DD;
  float acc = bq[t];
  for (int k = 0; k < DD; k++) acc = fmaf(nr[k], Wq[k * DD + t], acc);
  qg[g * DD + t] = acc;
  float ss = acc * acc;
  for (int off = 32; off > 0; off >>= 1) ss += __shfl_xor(ss, off, 64);
  if (t == 0) qnrm[g] = ss;
}

// ---- K4: partial argmax of score+gumbel: 4 generators x 256-j slice per item ----
__global__ __launch_bounds__(256) void sg_part(
    const float* __restrict__ nodes, const float* __restrict__ anodes,
    const float* __restrict__ hn, const int* __restrict__ gidx,
    const int* __restrict__ sc, const float* __restrict__ qg,
    const float* __restrict__ qnrm, float* __restrict__ party,
    int* __restrict__ partj) {
  __shared__ float sq[4][DD];
  __shared__ float sqn[4];
  __shared__ int si[4];
  __shared__ float wy[4][4];
  __shared__ int wj[4][4];
  int G = min(sc[0], GCAP);
  int nGq = (G + 3) >> 2;
  int total = nGq * SLICES;
  int t = threadIdx.x;
  int wid = t >> 6, lane = t & 63;
  uint2 ks = jax_subkey(2u);
  for (int item = blockIdx.x; item < total; item += gridDim.x) {
    int gq = item >> 5, s = item & 31;
    int g0 = gq * 4;
    __syncthreads();
    if (t < DD) {
      for (int u = 0; u < 4; u++)
        sq[u][t] = (g0 + u < G) ? qg[(g0 + u) * DD + t] : 0.0f;
    }
    if (t < 4) {
      int g = g0 + t;
      si[t] = (g < G) ? gidx[g] : -1;
      sqn[t] = (g < G) ? qnrm[g] : 1.0f;
    }
    __syncthreads();
    int j = s * 256 + t;
    float4 nv[16];
    const float4* np4 = (const float4*)(nodes + (size_t)j * DD);
    for (int k4 = 0; k4 < 16; k4++) nv[k4] = np4[k4];
    float hnj = hn[j];
    float act = anodes[j];
    float yy[4];
    for (int u = 0; u < 4; u++) {
      int iu = si[u];
      if (iu < 0) { yy[u] = -INFINITY; continue; }
      float num = 0.0f;
      for (int k4 = 0; k4 < 16; k4++) {
        const float4 qv = *(const float4*)&sq[u][4 * k4];
        num += nv[k4].x * qv.x + nv[k4].y * qv.y + nv[k4].z * qv.z + nv[k4].w * qv.w;
      }
      float denom = sqrtf(sqn[u] * hnj) + 1e-8f;
      float sco = num / denom;
      sco = fminf(fmaxf(sco, -10000.0f), 10000.0f);
      if (!(act > 0.0f)) sco = NEGV;
      if (j == iu) sco = NEGV;
      yy[u] = sco + jax_gumbel(ks, (uint32_t)iu * (uint32_t)NN + (uint32_t)j);
    }
    for (int u = 0; u < 4; u++) {
      float y = yy[u];
      int bj = j;
      for (int off = 32; off > 0; off >>= 1) {
        float oy = __shfl_xor(y, off, 64);
        int oj = __shfl_xor(bj, off, 64);
        if (oy > y || (oy == y && oj < bj)) { y = oy; bj = oj; }
      }
      if (lane == 0) { wy[u][wid] = y; wj[u][wid] = bj; }
    }
    __syncthreads();
    if (t < 4) {
      int u = t;
      if (g0 + u < G) {
        float y = wy[u][0];
        int bj = wj[u][0];
        for (int w = 1; w < 4; w++) {
          if (wy[u][w] > y || (wy[u][w] == y && wj[u][w] < bj)) { y = wy[u][w]; bj = wj[u][w]; }
        }
        party[(g0 + u) * SLICES + s] = y;
        partj[(g0 + u) * SLICES + s] = bj;
      }
    }
  }
}

// ---- K5: per-generator final argmax + duplicate-edge check ----
__global__ void sg_sel(const int* __restrict__ sc, const float* __restrict__ party,
                       const int* __restrict__ partj, const int* __restrict__ gidx,
                       const int* __restrict__ senders, const int* __restrict__ receivers,
                       int* __restrict__ sel, int* __restrict__ keptf) {
  int g = blockIdx.x;
  int G = min(sc[0], GCAP);
  if (g >= G) return;
  int t = threadIdx.x;
  __shared__ int js_s;
  __shared__ int ex;
  if (t < 64) {
    float y = (t < SLICES) ? party[g * SLICES + t] : -INFINITY;
    int bj = (t < SLICES) ? partj[g * SLICES + t] : 0x7fffffff;
    for (int off = 32; off > 0; off >>= 1) {
      float oy = __shfl_xor(y, off, 64);
      int oj = __shfl_xor(bj, off, 64);
      if (oy > y || (oy == y && oj < bj)) { y = oy; bj = oj; }
    }
    if (t == 0) { js_s = bj; ex = 0; }
  }
  __syncthreads();
  int i = gidx[g], js = js_s;
  int f = 0;
  for (int e = t; e < NE; e += 256)
    f |= (senders[e] == i && receivers[e] == js) ? 1 : 0;
  if (f) ex = 1;   // benign same-value race
  __syncthreads();
  if (t == 0) { sel[g] = js; keptf[g] = ex ? 0 : 1; }
}

// ---- K6: rank kept generators, clip n_gens (single block) ----
__global__ void sg_rank(const int* __restrict__ gidx, const int* __restrict__ sel,
                        const int* __restrict__ keptf, int* __restrict__ sc,
                        int* __restrict__ fid, int* __restrict__ fsel) {
  __shared__ int ts[256];
  int t = threadIdx.x;
  int G = min(sc[0], GCAP);
  int base = t * 32;
  int s = 0;
  for (int k = 0; k < 32; k++) { int g = base + k; if (g < G) s += keptf[g]; }
  ts[t] = s;
  __syncthreads();
  for (int off = 1; off < 256; off <<= 1) {
    int add = (t >= off) ? ts[t - off] : 0;
    __syncthreads();
    ts[t] += add;
    __syncthreads();
  }
  int r = ts[t] - s;
  for (int k = 0; k < 32; k++) {
    int g = base + k;
    if (g < G && keptf[g]) { fid[r] = gidx[g]; fsel[r] = sel[g]; r++; }
  }
  if (t == 255) {
    int kt = ts[255];
    int allowed = sc[2];
    int ng = kt > 0 ? kt : 0;
    if (ng > allowed) ng = allowed;
    sc[3] = kt; sc[4] = ng;
  }
}

// ---- K7: fused output writer: new_edges + nsend/nrec/naedges ----
__global__ void sg_write(const float* __restrict__ edges, const float* __restrict__ aedges,
                         const int* __restrict__ senders, const int* __restrict__ receivers,
                         const int* __restrict__ c, const int* __restrict__ sc,
                         const int* __restrict__ fid, const int* __restrict__ fsel,
                         float* __restrict__ out_edges, float* __restrict__ out_send,
                         float* __restrict__ out_rec, float* __restrict__ out_na) {
  int t4 = blockIdx.x * 256 + threadIdx.x;  // float4 index, NE*16 total
  float4 v = ((const float4*)edges)[t4];
  int e = t4 >> 4;
  int n = sc[4];
  int ce = c[e];
  int pidx = e - n - 1;
  int prev = (pidx >= 0) ? c[pidx] : 0;
  int na = ((ce - prev) > 0 && e != NE - 1) ? 1 : 0;
  float mv = na ? (1.0f - aedges[e]) : 0.0f;
  if (mv != 0.0f) {
    uint2 ke = jax_subkey(1u);
    uint32_t b = (uint32_t)t4 * 4u;
    v.x += jax_normal(ke, b + 0u) * mv;
    v.y += jax_normal(ke, b + 1u) * mv;
    v.z += jax_normal(ke, b + 2u) * mv;
    v.w += jax_normal(ke, b + 3u) * mv;
  }
  ((float4*)out_edges)[t4] = v;
  if ((t4 & 15) == 0) {
    int ea = sc[1], kept = sc[3];
    float ns, nr;
    if (!na) {
      ns = nr = (float)(NN - 1);
    } else if (mv > 0.0f) {
      int r = e - ea;
      bool ok = (r >= 0 && r < kept);
      ns = ok ? (float)fid[r] : 0.0f;   // segment_sum default is 0
      nr = ok ? (float)fsel[r] : 0.0f;
    } else {
      ns = (float)senders[e];
      nr = (float)receivers[e];
    }
    out_send[e] = ns;
    out_rec[e] = nr;
    out_na[e] = (float)na;
  }
}

extern "C" void kernel_launch(void* const* d_in, const int* in_sizes, int n_in,
                              void* d_out, int out_size, void* d_ws, size_t ws_size,
                              hipStream_t stream) {
  const float* nodes     = (const float*)d_in[0];
  const float* edges     = (const float*)d_in[1];
  const int*   receivers = (const int*)d_in[2];
  const int*   senders   = (const int*)d_in[3];
  const float* anodes    = (const float*)d_in[4];
  const float* aedges    = (const float*)d_in[5];
  const float* Wq        = (const float*)d_in[6];
  const float* bq        = (const float*)d_in[7];
  const float* Wp        = (const float*)d_in[8];
  const float* bp        = (const float*)d_in[9];

  float* out       = (float*)d_out;
  float* out_edges = out;
  float* out_send  = out + (size_t)NE * DD;
  float* out_rec   = out_send + NE;
  float* out_na    = out_rec + NE;

  int* sc     = (int*)d_ws;         // 8 scalars
  int* gens0  = sc + 8;             // NN
  int* gidx   = gens0 + NN;         // NN
  int* sel    = gidx + NN;          // GCAP
  int* keptf  = sel + GCAP;         // GCAP
  int* fid    = keptf + GCAP;       // GCAP
  int* fsel   = fid + GCAP;         // GCAP
  int* c      = fsel + GCAP;        // NE
  int* partj  = c + NE;             // GCAP*SLICES
  float* hn   = (float*)(partj + GCAP * SLICES);  // NN
  float* qg   = hn + NN;            // GCAP*DD
  float* qnrm = qg + GCAP * DD;     // GCAP
  float* party= qnrm + GCAP;        // GCAP*SLICES

  sg_gens  <<<NN / 4, 256, 0, stream>>>(nodes, Wp, bp, anodes, gens0, hn);
  sg_scan  <<<1, 256, 0, stream>>>(aedges, gens0, c, gidx, sc);
  sg_query <<<GCAP, 64, 0, stream>>>(nodes, Wq, bq, gidx, sc, qg, qnrm);
  sg_part  <<<2048, 256, 0, stream>>>(nodes, anodes, hn, gidx, sc, qg, qnrm, party, partj);
  sg_sel   <<<GCAP, 256, 0, stream>>>(sc, party, partj, gidx, senders, receivers, sel, keptf);
  sg_rank  <<<1, 256, 0, stream>>>(gidx, sel, keptf, sc, fid, fsel);
  sg_write <<<NE * DD / 4 / 256, 256, 0, stream>>>(edges, aedges, senders, receivers, c, sc,
                                                   fid, fsel, out_edges, out_send, out_rec,
                                                   out_na);
}